// Round 12
// baseline (30.012 us; speedup 1.0000x reference)
//
#include <hip/hip_runtime.h>
#include <math.h>

typedef _Float16 f16;
typedef f16 f16x8 __attribute__((ext_vector_type(8)));
typedef float f32x16 __attribute__((ext_vector_type(16)));

static constexpr int Bn = 16;
static constexpr int Kn = 4096;
static constexpr int NPTS = Bn * Kn;    // 65536
static constexpr int MGRID = 512;       // qg8(16) x b(16) x dir(2)
static constexpr int NPSUM = 1024;      // psum keeps the OLD 1024-slot layout
static constexpr float WBIG = 49152.0f; // exact in fp16
static constexpr float QMIN0 = 3e37f;

// Round-12: R11 base (fused prep, best at 28.0) + ONE change: the inner
// loop issues MFMAs in enforced clusters of FOUR into four named
// accumulators (d0..d3), with sched_group_barrier pinning [4xMFMA][32xVALU]
// so the compiler cannot re-serialize into mfma->drain->mfma. Rationale:
// the elimination ledger (R3/R7 traffic 2x, R8 waves 2x, R9 depth-2
// unpinned, R11 +1100 VALU inst) leaves exactly one mechanism standing:
// MFMA result-latency serialization (~150-200 cyc D-ready for the 4-pass
// 32x32 shape) behind a single live d buffer. Depth-4 + pinning covers
// ~4x32=128 cyc of issue per wait and doubles per-wave independence vs
// R9 (which the scheduler was free to undo). Per-qt min3 chains keep
// their exact operand order -> bitwise-identical output. VGPR ~190 < 256
// cap at (256,2) -> no clamp-spill (tripwire: fused WRITE_SIZE balloon).
__global__ __launch_bounds__(256, 2) void chamfer_fused_kernel(
        const float* __restrict__ pred, const float* __restrict__ target,
        const int* __restrict__ mask,
        float* __restrict__ psum, unsigned int* __restrict__ cnt4) {
    int bid = blockIdx.x;
    int lin = (bid & 7) * 64 + (bid >> 3);    // XCD-contiguous logical id
    int qg8 = lin & 15; lin >>= 4;            // qg8(16) fastest, b(16), dir(2)
    int b   = lin & 15; lin >>= 4;
    int dir = lin;                            // 0: queries=pred, refs=target
    int j0 = dir * 512 + b * 32 + qg8 * 2;    // old logical psum slots
    int j1 = j0 + 1;

    const float* __restrict__ Araw = dir ? pred : target;  // refs
    const float* __restrict__ Braw = dir ? target : pred;  // queries

    int tid = threadIdx.x;
    int w = tid >> 6, l = tid & 63;
    int r = l & 31, g = l >> 5;

    __shared__ float comb[4][8][64];

    // opaque zero C-operand: runtime value IS 0, provenance hidden.
    float zf;
    asm volatile("v_mov_b32 %0, 0" : "=v"(zf));
    f32x16 cz;
    #pragma unroll
    for (int i = 0; i < 16; ++i) cz[i] = zf;

    const f16 one = (f16)1.0f, zero = (f16)0.0f;

    // ---- B fragments for this block's 8 query tiles (same bit-values as
    // old prep's B slots: B = {xh,xl,xh,yh,yl,yh,zh,zl | zh,1,1,whB,wlB,0,0,0})
    f16x8 bq[8];
    unsigned int bcnt[8];
    #pragma unroll
    for (int qt = 0; qt < 8; ++qt) {
        int idx = b * 4096 + (qg8 * 8 + qt) * 32 + r;
        bool valid = mask[idx] != 0;
        float x = Braw[idx * 3 + 0], y = Braw[idx * 3 + 1], z = Braw[idx * 3 + 2];
        if (!valid) { x = 0.0f; y = 0.0f; z = 0.0f; }
        float wv = fmaf(x, x, fmaf(y, y, z * z));
        f16 xh = (f16)x, yh = (f16)y, zh = (f16)z;
        f16 xl = (f16)(x - (float)xh), yl = (f16)(y - (float)yh), zl = (f16)(z - (float)zh);
        f16 whB, wlB;
        if (valid) { f16 wh = (f16)wv; whB = wh; wlB = (f16)(wv - (float)wh); }
        else       { whB = (f16)(-WBIG); wlB = zero; }
        f16x8 blo = {xh, xl, xh, yh, yl, yh, zh, zl};
        f16x8 bhi = {zh, one, one, whB, wlB, zero, zero, zero};
        bq[qt] = g ? bhi : blo;
        // lanes r and r+32 hold the same point -> popcll is 2x the count
        unsigned long long mb = __ballot(valid);
        bcnt[qt] = (unsigned int)__popcll(mb) >> 1;
    }
    // dir=0 blocks own cnt4 slots b*64 + qg8*4 + m (64 consecutive points
    // each = qt pair (2m,2m+1)) — same values as old prep's ballots.
    if (dir == 0 && w == 0 && l == 0) {
        #pragma unroll
        for (int m = 0; m < 4; ++m)
            cnt4[b * 64 + qg8 * 4 + m] = bcnt[2 * m] + bcnt[2 * m + 1];
    }

    float qA[8], qB[8];
    #pragma unroll
    for (int qt = 0; qt < 8; ++qt) { qA[qt] = QMIN0; qB[qt] = QMIN0; }

    // wave w covers ref tiles rt = w + 4t, t = 0..31 (R7's exact order).
    #pragma unroll 4
    for (int t = 0; t < 32; ++t) {
        int idxA = b * 4096 + (w + 4 * t) * 32 + r;
        bool valid = mask[idxA] != 0;
        float x = Araw[idxA * 3 + 0], y = Araw[idxA * 3 + 1], z = Araw[idxA * 3 + 2];
        if (!valid) { x = 0.0f; y = 0.0f; z = 0.0f; }
        // A slots (bit-identical to old prep):
        // A = {m2xh,m2xh,m2xl,m2yh,m2yh,m2yl,m2zh,m2zh | m2zl,whA,wlA,1,1,0,0,0}
        float wv = fmaf(x, x, fmaf(y, y, z * z));
        f16 xh = (f16)x, yh = (f16)y, zh = (f16)z;
        f16 xl = (f16)(x - (float)xh), yl = (f16)(y - (float)yh), zl = (f16)(z - (float)zh);
        f16 m2xh = (f16)(-2.0f * (float)xh), m2xl = (f16)(-2.0f * (float)xl);
        f16 m2yh = (f16)(-2.0f * (float)yh), m2yl = (f16)(-2.0f * (float)yl);
        f16 m2zh = (f16)(-2.0f * (float)zh), m2zl = (f16)(-2.0f * (float)zl);
        f16 whA, wlA;
        if (valid) { f16 wh = (f16)wv; whA = wh; wlA = (f16)(wv - (float)wh); }
        else       { whA = (f16)WBIG; wlA = zero; }
        f16x8 alo = {m2xh, m2xh, m2xl, m2yh, m2yh, m2yl, m2zh, m2zh};
        f16x8 ahi = {m2zl, whA, wlA, one, one, zero, zero, zero};
        f16x8 a = g ? ahi : alo;

        // Two enforced clusters of 4 MFMAs, each followed by its 32-min3
        // drain. Named accumulators (static indices, rule-#20 safe).
        #pragma unroll
        for (int qp = 0; qp < 2; ++qp) {
            const int q0 = 4 * qp + 0, q1 = 4 * qp + 1;
            const int q2 = 4 * qp + 2, q3 = 4 * qp + 3;
            f32x16 d0 = __builtin_amdgcn_mfma_f32_32x32x16_f16(a, bq[q0], cz, 0, 0, 0);
            f32x16 d1 = __builtin_amdgcn_mfma_f32_32x32x16_f16(a, bq[q1], cz, 0, 0, 0);
            f32x16 d2 = __builtin_amdgcn_mfma_f32_32x32x16_f16(a, bq[q2], cz, 0, 0, 0);
            f32x16 d3 = __builtin_amdgcn_mfma_f32_32x32x16_f16(a, bq[q3], cz, 0, 0, 0);
            #pragma unroll
            for (int i = 0; i < 4; ++i) {
                qA[q0] = fminf(fminf(qA[q0], d0[4 * i + 0]), d0[4 * i + 1]);  // -> v_min3
                qB[q0] = fminf(fminf(qB[q0], d0[4 * i + 2]), d0[4 * i + 3]);
            }
            #pragma unroll
            for (int i = 0; i < 4; ++i) {
                qA[q1] = fminf(fminf(qA[q1], d1[4 * i + 0]), d1[4 * i + 1]);
                qB[q1] = fminf(fminf(qB[q1], d1[4 * i + 2]), d1[4 * i + 3]);
            }
            #pragma unroll
            for (int i = 0; i < 4; ++i) {
                qA[q2] = fminf(fminf(qA[q2], d2[4 * i + 0]), d2[4 * i + 1]);
                qB[q2] = fminf(fminf(qB[q2], d2[4 * i + 2]), d2[4 * i + 3]);
            }
            #pragma unroll
            for (int i = 0; i < 4; ++i) {
                qA[q3] = fminf(fminf(qA[q3], d3[4 * i + 0]), d3[4 * i + 1]);
                qB[q3] = fminf(fminf(qB[q3], d3[4 * i + 2]), d3[4 * i + 3]);
            }
            // Pin the schedule: 4 MFMAs clustered, then the 32-min3 drain.
            __builtin_amdgcn_sched_group_barrier(0x008, 4, 0);   // MFMA x4
            __builtin_amdgcn_sched_group_barrier(0x002, 32, 0);  // VALU x32
        }
    }

    #pragma unroll
    for (int qt = 0; qt < 8; ++qt) comb[w][qt][l] = fminf(qA[qt], qB[qt]);
    __syncthreads();

    // Two independent reductions, each the EXACT old-block computation.
    float c0 = 0.0f, c1 = 0.0f;
    if (tid < 128) {
        int qt = tid >> 5, c = tid & 31;
        float m0 = QMIN0, m1 = QMIN0;
        #pragma unroll
        for (int ww = 0; ww < 4; ++ww)
            #pragma unroll
            for (int h = 0; h < 2; ++h) {
                m0 = fminf(m0, comb[ww][qt][h * 32 + c]);
                m1 = fminf(m1, comb[ww][qt + 4][h * 32 + c]);
            }
        // m < -1e4 marks an invalid query (w_q = -WBIG); contributes 0
        c0 = (m0 < -1e4f) ? 0.0f : sqrtf(fmaxf(m0, 1e-12f));
        c1 = (m1 < -1e4f) ? 0.0f : sqrtf(fmaxf(m1, 1e-12f));
    }
    for (int off = 32; off; off >>= 1) {
        c0 += __shfl_down(c0, off, 64);
        c1 += __shfl_down(c1, off, 64);
    }
    __shared__ float ps0[4], ps1[4];
    if ((tid & 63) == 0) { ps0[tid >> 6] = c0; ps1[tid >> 6] = c1; }
    __syncthreads();
    if (tid == 0) {
        psum[j0] = ps0[0] + ps0[1] + ps0[2] + ps0[3];
        psum[j1] = ps1[0] + ps1[1] + ps1[2] + ps1[3];
    }
}

__global__ __launch_bounds__(256) void final_kernel(
        const unsigned int* __restrict__ cnt4, const float* __restrict__ psum,
        float* __restrict__ out) {
    int t = threadIdx.x;
    unsigned int c = 0;
    float s = 0.0f;
    #pragma unroll
    for (int i = 0; i < 4; ++i) {
        c += cnt4[t + 256 * i];
        s += psum[t + 256 * i];
    }
    for (int off = 32; off; off >>= 1) {
        c += __shfl_down(c, off, 64);
        s += __shfl_down(s, off, 64);
    }
    __shared__ unsigned int cs[4];
    __shared__ float ss[4];
    if ((t & 63) == 0) { cs[t >> 6] = c; ss[t >> 6] = s; }
    __syncthreads();
    if (t == 0) {
        unsigned int C = cs[0] + cs[1] + cs[2] + cs[3];
        float S = ss[0] + ss[1] + ss[2] + ss[3];
        out[0] = S * 0.5f / ((float)C + 1e-8f);
    }
}

extern "C" void kernel_launch(void* const* d_in, const int* in_sizes, int n_in,
                              void* d_out, int out_size, void* d_ws, size_t ws_size,
                              hipStream_t stream) {
    const float* pred = (const float*)d_in[0];
    const float* target = (const float*)d_in[1];
    const int* mask = (const int*)d_in[2];
    float* out = (float*)d_out;

    // ws: [psum 4K | cnt4 4K]
    char* ws = (char*)d_ws;
    float* psum = (float*)ws;
    unsigned int* cnt4 = (unsigned int*)(ws + NPSUM * sizeof(float));

    chamfer_fused_kernel<<<MGRID, 256, 0, stream>>>(
        pred, target, mask, psum, cnt4);
    final_kernel<<<1, 256, 0, stream>>>(cnt4, psum, out);
}